// Round 7
// baseline (57.960 us; speedup 1.0000x reference)
//
#include <hip/hip_runtime.h>

#define NN 4096
#define FIN 256
#define FOUT 64
#define NH 4
#define CAP 128    // max edges/row; Binomial(4096,0.01) mean 42, P(>127) ~ 1e-30
#define SCANB 1024 // scan blocks: 4 rows each (one wave per row)
#define SDB 256    // src/dst blocks appended to scan kernel: 16 nodes x 4 heads

// popcount of mask restricted to lanes strictly below mine
__device__ __forceinline__ int mbcnt64(unsigned long long m) {
    return __builtin_amdgcn_mbcnt_hi((unsigned)(m >> 32),
           __builtin_amdgcn_mbcnt_lo((unsigned)m, 0));
}

// ---------------------------------------------------------------------------
// K1: h_prime[h,n,:] = h[n,:] @ w[h]. Wave = 4 nodes x ALL 4 heads (amortizes
// each LDS h-broadcast over 16 FMAs). 1024 waves. lane = output feature.
// ---------------------------------------------------------------------------
__global__ __launch_bounds__(256) void gat_hprime(
    const float* __restrict__ h, const float* __restrict__ w,
    float* __restrict__ h_prime)
{
    const int t = threadIdx.x, wv = t >> 6, lane = t & 63;
    const int n0 = (blockIdx.x * 4 + wv) * 4;
    __shared__ float hs[4][4 * FIN];   // 16 KB, per-wave private tile

    // stage 4 h rows, coalesced float4 (same-wave produce/consume, no barrier)
    const float4* hsrc = (const float4*)(h + (size_t)n0 * FIN);
    float4* hdst = (float4*)hs[wv];
#pragma unroll
    for (int r = 0; r < 4; ++r) hdst[r * 64 + lane] = hsrc[r * 64 + lane];

    float acc[4][NH];
#pragma unroll
    for (int n = 0; n < 4; ++n)
#pragma unroll
        for (int hh = 0; hh < NH; ++hh) acc[n][hh] = 0.f;

    const float* wp = w + lane;   // + hh*FIN*FOUT + f*FOUT, coalesced over lane
#pragma unroll 2
    for (int f0 = 0; f0 < FIN; f0 += 4) {
        float wr[NH][4];
#pragma unroll
        for (int hh = 0; hh < NH; ++hh)
#pragma unroll
            for (int j = 0; j < 4; ++j)
                wr[hh][j] = wp[hh * FIN * FOUT + (f0 + j) * FOUT];
#pragma unroll
        for (int n = 0; n < 4; ++n) {
            const float4 hv = *(const float4*)&hs[wv][n * FIN + f0];  // broadcast
#pragma unroll
            for (int hh = 0; hh < NH; ++hh) {
                acc[n][hh] = fmaf(hv.x, wr[hh][0], acc[n][hh]);
                acc[n][hh] = fmaf(hv.y, wr[hh][1], acc[n][hh]);
                acc[n][hh] = fmaf(hv.z, wr[hh][2], acc[n][hh]);
                acc[n][hh] = fmaf(hv.w, wr[hh][3], acc[n][hh]);
            }
        }
    }
#pragma unroll
    for (int n = 0; n < 4; ++n)
#pragma unroll
        for (int hh = 0; hh < NH; ++hh)
            h_prime[(size_t)(hh * NN + n0 + n) * FOUT + lane] = acc[n][hh];
}

// ---------------------------------------------------------------------------
// K2: blocks [0,SCANB): adjacency scan -> CSR (register-staged, no atomics).
//     blocks [SCANB,+SDB): src/dst logits from h_prime (16 nodes, wave=head).
// ---------------------------------------------------------------------------
__global__ __launch_bounds__(256) void gat_scan(
    const int* __restrict__ adj, const float* __restrict__ h_prime,
    const float* __restrict__ a_src, const float* __restrict__ a_dst,
    int* __restrict__ counts, int* __restrict__ edges,
    float* __restrict__ src, float* __restrict__ dst)
{
    const int b = blockIdx.x, t = threadIdx.x, lane = t & 63;
    if (b < SCANB) {
        const int row = b * 4 + (t >> 6);
        const int4* arow = (const int4*)(adj + (size_t)row * NN);

        int4 buf[16];
#pragma unroll
        for (int it = 0; it < 16; ++it) buf[it] = arow[it * 64 + lane];

        int pos[16];
        int run = 0;
#pragma unroll
        for (int it = 0; it < 16; ++it) {
            const unsigned long long b0 = __ballot(buf[it].x != 0);
            const unsigned long long b1 = __ballot(buf[it].y != 0);
            const unsigned long long b2 = __ballot(buf[it].z != 0);
            const unsigned long long b3 = __ballot(buf[it].w != 0);
            pos[it] = run + mbcnt64(b0) + mbcnt64(b1) + mbcnt64(b2) + mbcnt64(b3);
            run += __popcll(b0) + __popcll(b1) + __popcll(b2) + __popcll(b3);
        }

        int* erow = edges + (size_t)row * CAP;
#pragma unroll
        for (int it = 0; it < 16; ++it) {
            int p = pos[it];
            const int col0 = (it * 64 + lane) * 4;
            if (buf[it].x) { if (p < CAP) erow[p] = col0;     ++p; }
            if (buf[it].y) { if (p < CAP) erow[p] = col0 + 1; ++p; }
            if (buf[it].z) { if (p < CAP) erow[p] = col0 + 2; ++p; }
            if (buf[it].w) { if (p < CAP) erow[p] = col0 + 3; ++p; }
        }
        if (lane == 0) counts[row] = run;
    } else {
        // src/dst: wave = head, 16 nodes per wave, 4 lanes per node
        const int hh = t >> 6, nd = lane >> 2, ch = lane & 3;
        const int node = (b - SCANB) * 16 + nd;
        const float4* hp4 = (const float4*)(h_prime +
                             (size_t)(hh * NN + node) * FOUT) + ch * 4;
        float s = 0.f, d = 0.f;
#pragma unroll
        for (int r = 0; r < 4; ++r) {
            const float4 v  = hp4[r];
            const float4 as = *(const float4*)(a_src + hh * FOUT + ch * 16 + r * 4);
            const float4 ad = *(const float4*)(a_dst + hh * FOUT + ch * 16 + r * 4);
            s += v.x * as.x + v.y * as.y + v.z * as.z + v.w * as.w;
            d += v.x * ad.x + v.y * ad.y + v.z * ad.z + v.w * ad.w;
        }
        s += __shfl_xor(s, 1, 64); s += __shfl_xor(s, 2, 64);
        d += __shfl_xor(d, 1, 64); d += __shfl_xor(d, 2, 64);
        if (ch == 0) { src[hh * NN + node] = s; dst[hh * NN + node] = d; }
    }
}

// ---------------------------------------------------------------------------
// K3: per-row softmax + gather from CSR. Block = row, wave = head.
// ---------------------------------------------------------------------------
__global__ __launch_bounds__(256) void gat_attn(
    const int* __restrict__ counts, const int* __restrict__ edges,
    const float* __restrict__ h_prime, const float* __restrict__ src,
    const float* __restrict__ dst, const float* __restrict__ bias,
    float* __restrict__ out)
{
    const int i    = blockIdx.x;
    const int t    = threadIdx.x;
    const int wave = t >> 6, lane = t & 63;

    __shared__ int   idx_l[CAP];
    __shared__ float sc[NH][CAP];
    __shared__ float inv_sum[NH];

    const int count = min(counts[i], CAP);

    if (t < count) {
        const int j = edges[(size_t)i * CAP + t];
        idx_l[t] = j;
#pragma unroll
        for (int hh = 0; hh < NH; ++hh) {
            float s = src[hh * NN + i] + dst[hh * NN + j];
            sc[hh][t] = (s >= 0.f) ? s : 0.2f * s;   // leaky_relu(0.2)
        }
    }
    __syncthreads();

    {
        const int hh = wave;
        float m = -3.4e38f;
        for (int p = lane; p < count; p += 64) m = fmaxf(m, sc[hh][p]);
#pragma unroll
        for (int off = 32; off >= 1; off >>= 1) m = fmaxf(m, __shfl_xor(m, off, 64));
        float e = 0.f;
        for (int p = lane; p < count; p += 64) {
            float v = __expf(sc[hh][p] - m);
            sc[hh][p] = v;
            e += v;
        }
#pragma unroll
        for (int off = 32; off >= 1; off >>= 1) e += __shfl_xor(e, off, 64);
        if (lane == 0) inv_sum[hh] = 1.f / e;
    }
    __syncthreads();

    float acc = 0.f;
    const float* hp = h_prime + (size_t)(wave * NN) * FOUT + lane;
    for (int p = 0; p < count; ++p)
        acc = fmaf(sc[wave][p], hp[(size_t)idx_l[p] * FOUT], acc);
    out[(size_t)i * (NH * FOUT) + wave * FOUT + lane] = acc * inv_sum[wave] + bias[lane];
}

extern "C" void kernel_launch(void* const* d_in, const int* in_sizes, int n_in,
                              void* d_out, int out_size, void* d_ws, size_t ws_size,
                              hipStream_t stream) {
    const float* h     = (const float*)d_in[0];
    const int*   adj   = (const int*)d_in[1];
    const float* w     = (const float*)d_in[2];
    const float* a_src = (const float*)d_in[3];
    const float* a_dst = (const float*)d_in[4];
    const float* bias  = (const float*)d_in[5];
    float* out = (float*)d_out;

    float* wsf     = (float*)d_ws;
    float* h_prime = wsf;                        // NH*NN*FOUT floats = 4 MB
    float* src     = h_prime + NH * NN * FOUT;   // NH*NN
    float* dst     = src + NH * NN;              // NH*NN
    int*   counts  = (int*)(dst + NH * NN);      // NN ints
    int*   edges   = counts + NN;                // NN*CAP ints = 2 MB

    gat_hprime<<<256, 256, 0, stream>>>(h, w, h_prime);
    gat_scan<<<SCANB + SDB, 256, 0, stream>>>(adj, h_prime, a_src, a_dst,
                                              counts, edges, src, dst);
    gat_attn<<<NN, 256, 0, stream>>>(counts, edges, h_prime, src, dst, bias, out);
}

// Round 8
// 55.584 us; speedup vs baseline: 1.0428x; 1.0428x over previous
//
#include <hip/hip_runtime.h>

#define NN 4096
#define FIN 256
#define FOUT 64
#define NH 4
#define CAP 128    // max edges/row; Binomial(4096,0.01) mean 42, P(>127) ~ 1e-30

// popcount of mask restricted to lanes strictly below mine
__device__ __forceinline__ int mbcnt64(unsigned long long m) {
    return __builtin_amdgcn_mbcnt_hi((unsigned)(m >> 32),
           __builtin_amdgcn_mbcnt_lo((unsigned)m, 0));
}

// ---------------------------------------------------------------------------
// K1: h_prime[h,n,:] = h[n,:] @ w[h] for ALL 4 heads per wave (amortizes each
// LDS h-broadcast over 16 FMAs). 256 blocks x 4 waves x 4 nodes. lane = o.
// src/dst logits reduced in-register from acc (no h_prime re-read).
// ---------------------------------------------------------------------------
__global__ __launch_bounds__(256) void gat_hprime(
    const float* __restrict__ h, const float* __restrict__ w,
    const float* __restrict__ a_src, const float* __restrict__ a_dst,
    float* __restrict__ h_prime, float* __restrict__ src, float* __restrict__ dst)
{
    const int t = threadIdx.x, wv = t >> 6, lane = t & 63;
    const int n0 = (blockIdx.x * 4 + wv) * 4;
    __shared__ float hs[4][4 * FIN];   // 16 KB, per-wave private tile

    // stage 4 h rows, coalesced float4 (same-wave produce/consume, no barrier)
    const float4* hsrc = (const float4*)(h + (size_t)n0 * FIN);
    float4* hdst = (float4*)hs[wv];
#pragma unroll
    for (int r = 0; r < 4; ++r) hdst[r * 64 + lane] = hsrc[r * 64 + lane];

    float acc[4][NH];
#pragma unroll
    for (int n = 0; n < 4; ++n)
#pragma unroll
        for (int hh = 0; hh < NH; ++hh) acc[n][hh] = 0.f;

    const float* wp = w + lane;   // + hh*FIN*FOUT + f*FOUT, coalesced over lane
#pragma unroll 2
    for (int f0 = 0; f0 < FIN; f0 += 4) {
        float wr[NH][4];
#pragma unroll
        for (int hh = 0; hh < NH; ++hh)
#pragma unroll
            for (int j = 0; j < 4; ++j)
                wr[hh][j] = wp[hh * FIN * FOUT + (f0 + j) * FOUT];
#pragma unroll
        for (int n = 0; n < 4; ++n) {
            const float4 hv = *(const float4*)&hs[wv][n * FIN + f0];  // broadcast
#pragma unroll
            for (int hh = 0; hh < NH; ++hh) {
                acc[n][hh] = fmaf(hv.x, wr[hh][0], acc[n][hh]);
                acc[n][hh] = fmaf(hv.y, wr[hh][1], acc[n][hh]);
                acc[n][hh] = fmaf(hv.z, wr[hh][2], acc[n][hh]);
                acc[n][hh] = fmaf(hv.w, wr[hh][3], acc[n][hh]);
            }
        }
    }

    float as[NH], ad[NH];
#pragma unroll
    for (int hh = 0; hh < NH; ++hh) {
        as[hh] = a_src[hh * FOUT + lane];
        ad[hh] = a_dst[hh * FOUT + lane];
    }
#pragma unroll
    for (int n = 0; n < 4; ++n)
#pragma unroll
        for (int hh = 0; hh < NH; ++hh) {
            h_prime[(size_t)(hh * NN + n0 + n) * FOUT + lane] = acc[n][hh];
            float vs = acc[n][hh] * as[hh];
            float vd = acc[n][hh] * ad[hh];
#pragma unroll
            for (int off = 32; off >= 1; off >>= 1) {
                vs += __shfl_xor(vs, off, 64);
                vd += __shfl_xor(vd, off, 64);
            }
            if (lane == 0) {
                src[hh * NN + n0 + n] = vs;
                dst[hh * NN + n0 + n] = vd;
            }
        }
}

// ---------------------------------------------------------------------------
// K2: fused scan+attn. Block = row i. Reads the 16 KB adj row directly,
// ballot-compacts edge indices into LDS (deterministic chunk-prefix order),
// then scores -> per-head softmax (wave = head) -> 8-deep batched gather.
// No edges/counts round-trip through HBM.
// ---------------------------------------------------------------------------
__global__ __launch_bounds__(256) void gat_attn(
    const int* __restrict__ adj, const float* __restrict__ h_prime,
    const float* __restrict__ src, const float* __restrict__ dst,
    const float* __restrict__ bias, float* __restrict__ out)
{
    const int i = blockIdx.x, t = threadIdx.x, wv = t >> 6, lane = t & 63;

    __shared__ int   idx_l[CAP];
    __shared__ float sc[NH][CAP];
    __shared__ int   ccnt[16];
    __shared__ float inv_sum[NH];

    // Phase A: issue my 4 int4 loads of the row back-to-back (wave wv owns
    // int4 range [wv*256, wv*256+256) -> whole 16 KB row in flight per block)
    const int4* arow = (const int4*)(adj + (size_t)i * NN);
    int4 a[4];
#pragma unroll
    for (int it = 0; it < 4; ++it) a[it] = arow[wv * 256 + it * 64 + lane];

    // Phase B: ballots -> within-chunk offset + per-chunk count
    int myoff[4];
#pragma unroll
    for (int it = 0; it < 4; ++it) {
        const unsigned long long b0 = __ballot(a[it].x != 0);
        const unsigned long long b1 = __ballot(a[it].y != 0);
        const unsigned long long b2 = __ballot(a[it].z != 0);
        const unsigned long long b3 = __ballot(a[it].w != 0);
        myoff[it] = mbcnt64(b0) + mbcnt64(b1) + mbcnt64(b2) + mbcnt64(b3);
        if (lane == 0)
            ccnt[wv * 4 + it] = __popcll(b0) + __popcll(b1) +
                                __popcll(b2) + __popcll(b3);
    }
    __syncthreads();

    // chunk-prefix (16 chunks, column order = wv*4+it) -> deterministic layout
    int cb[4];
    int s = 0;
#pragma unroll
    for (int k = 0; k < 16; ++k) {
        if ((k >> 2) == wv) cb[k & 3] = s;
        s += ccnt[k];
    }
    const int count = min(s, CAP);
    const int cpad  = (count + 7) & ~7;

    // Phase C: scatter edge columns into LDS
#pragma unroll
    for (int it = 0; it < 4; ++it) {
        int p = cb[it] + myoff[it];
        const int col0 = (wv * 256 + it * 64 + lane) * 4;
        if (a[it].x) { if (p < CAP) idx_l[p] = col0;     ++p; }
        if (a[it].y) { if (p < CAP) idx_l[p] = col0 + 1; ++p; }
        if (a[it].z) { if (p < CAP) idx_l[p] = col0 + 2; ++p; }
        if (a[it].w) { if (p < CAP) idx_l[p] = col0 + 3; ++p; }
    }
    __syncthreads();

    // scores (t -> edge t) + zero-padding to cpad (contributes 0 to gather)
    if (t < count) {
        const int j = idx_l[t];
#pragma unroll
        for (int hh = 0; hh < NH; ++hh) {
            float v = src[hh * NN + i] + dst[hh * NN + j];
            sc[hh][t] = (v >= 0.f) ? v : 0.2f * v;   // leaky_relu(0.2)
        }
    } else if (t < cpad) {
        idx_l[t] = 0;
#pragma unroll
        for (int hh = 0; hh < NH; ++hh) sc[hh][t] = 0.f;
    }
    __syncthreads();

    // per-head softmax (wave = head); padded entries stay exactly 0
    {
        float m = -3.4e38f;
        for (int p = lane; p < count; p += 64) m = fmaxf(m, sc[wv][p]);
#pragma unroll
        for (int off = 32; off >= 1; off >>= 1) m = fmaxf(m, __shfl_xor(m, off, 64));
        float e = 0.f;
        for (int p = lane; p < count; p += 64) {
            float v = __expf(sc[wv][p] - m);
            sc[wv][p] = v;
            e += v;
        }
#pragma unroll
        for (int off = 32; off >= 1; off >>= 1) e += __shfl_xor(e, off, 64);
        if (lane == 0) inv_sum[wv] = 1.f / e;
    }
    __syncthreads();

    // gather, 8 independent loads in flight per batch
    float accv = 0.f;
    const float* hp = h_prime + (size_t)(wv * NN) * FOUT + lane;
    for (int p0 = 0; p0 < cpad; p0 += 8) {
        int   jj[8]; float vv[8]; float ww[8];
#pragma unroll
        for (int k = 0; k < 8; ++k) jj[k] = idx_l[p0 + k];
#pragma unroll
        for (int k = 0; k < 8; ++k) vv[k] = hp[(size_t)jj[k] * FOUT];
#pragma unroll
        for (int k = 0; k < 8; ++k) ww[k] = sc[wv][p0 + k];
#pragma unroll
        for (int k = 0; k < 8; ++k) accv = fmaf(ww[k], vv[k], accv);
    }
    out[(size_t)i * (NH * FOUT) + wv * FOUT + lane] = accv * inv_sum[wv] + bias[lane];
}

extern "C" void kernel_launch(void* const* d_in, const int* in_sizes, int n_in,
                              void* d_out, int out_size, void* d_ws, size_t ws_size,
                              hipStream_t stream) {
    const float* h     = (const float*)d_in[0];
    const int*   adj   = (const int*)d_in[1];
    const float* w     = (const float*)d_in[2];
    const float* a_src = (const float*)d_in[3];
    const float* a_dst = (const float*)d_in[4];
    const float* bias  = (const float*)d_in[5];
    float* out = (float*)d_out;

    float* wsf     = (float*)d_ws;
    float* h_prime = wsf;                        // NH*NN*FOUT floats = 4 MB
    float* src     = h_prime + NH * NN * FOUT;   // NH*NN
    float* dst     = src + NH * NN;              // NH*NN

    gat_hprime<<<256, 256, 0, stream>>>(h, w, a_src, a_dst, h_prime, src, dst);
    gat_attn<<<NN, 256, 0, stream>>>(adj, h_prime, src, dst, bias, out);
}

// Round 9
// 52.666 us; speedup vs baseline: 1.1005x; 1.0554x over previous
//
#include <hip/hip_runtime.h>

#define NN 4096
#define FIN 256
#define FOUT 64
#define NH 4
#define CAP 128    // max edges/row; Binomial(4096,0.01) P(>127) ~ 1e-30
#define CPB 1024   // compress blocks: 4 rows each (one wave per row)
#define HPBK 512   // hprime blocks: 8 nodes x 4 heads (wave = head)

// ---------------------------------------------------------------------------
// K1, two independent block types:
//  [0,CPB):    adj (64MB int) -> ballot bitmask (2MB). Pure stream.
//              Encoding: bits[row][it*4+k] bit l  <->  col = it*256 + 4*l + k.
//  [CPB,+HPBK): split-K hprime. lane=(fi,og): fi=f-phase (lane>>4), og=o-quad
//              (lane&15). No LDS, no broadcast reads; fi-reduce via shfl_xor.
//              Also emits src/dst logits (og-reduce from registers).
// ---------------------------------------------------------------------------
__global__ __launch_bounds__(256) void gat_prep(
    const float* __restrict__ h, const int* __restrict__ adj,
    const float* __restrict__ w, const float* __restrict__ a_src,
    const float* __restrict__ a_dst,
    float* __restrict__ h_prime, float* __restrict__ src, float* __restrict__ dst,
    unsigned long long* __restrict__ bits)
{
    const int b = blockIdx.x, t = threadIdx.x, wv = t >> 6, lane = t & 63;

    if (b < CPB) {
        // ---------------- compress: one wave owns one row ----------------
        const int row = b * 4 + wv;
        const int4* arow = (const int4*)(adj + (size_t)row * NN);
        int4 buf[16];
#pragma unroll
        for (int it = 0; it < 16; ++it) buf[it] = arow[it * 64 + lane];

        unsigned long long* brow = bits + (size_t)row * 64;
#pragma unroll
        for (int it = 0; it < 16; ++it) {
            const unsigned long long b0 = __ballot(buf[it].x != 0);
            const unsigned long long b1 = __ballot(buf[it].y != 0);
            const unsigned long long b2 = __ballot(buf[it].z != 0);
            const unsigned long long b3 = __ballot(buf[it].w != 0);
            unsigned long long mk = b0;            // uniform values, lane-select
            mk = ((lane & 3) == 1) ? b1 : mk;
            mk = ((lane & 3) == 2) ? b2 : mk;
            mk = ((lane & 3) == 3) ? b3 : mk;
            if (lane < 4) brow[it * 4 + lane] = mk;
        }
    } else {
        // ---------------- split-K hprime: wave = head, 8 nodes ----------------
        const int n0 = (b - CPB) * 8;
        const int hh = wv;
        const int og = lane & 15, fi = lane >> 4;

        float4 acc[8];
#pragma unroll
        for (int n = 0; n < 8; ++n) acc[n] = make_float4(0.f, 0.f, 0.f, 0.f);

        const float* wbase = w + (size_t)hh * FIN * FOUT + 4 * og;

#pragma unroll 2
        for (int kc = 0; kc < 16; ++kc) {
            const int fb = kc * 16 + 4 * fi;       // my f-quad this chunk
            float4 wq[4], hq[8];
#pragma unroll
            for (int j = 0; j < 4; ++j)
                wq[j] = *(const float4*)(wbase + (size_t)(fb + j) * FOUT);
#pragma unroll
            for (int n = 0; n < 8; ++n)
                hq[n] = *(const float4*)(h + (size_t)(n0 + n) * FIN + fb);
#pragma unroll
            for (int n = 0; n < 8; ++n) {
#pragma unroll
                for (int j = 0; j < 4; ++j) {
                    const float hv = (j == 0) ? hq[n].x : (j == 1) ? hq[n].y
                                    : (j == 2) ? hq[n].z : hq[n].w;   // static j
                    acc[n].x = fmaf(hv, wq[j].x, acc[n].x);
                    acc[n].y = fmaf(hv, wq[j].y, acc[n].y);
                    acc[n].z = fmaf(hv, wq[j].z, acc[n].z);
                    acc[n].w = fmaf(hv, wq[j].w, acc[n].w);
                }
            }
        }

        // reduce partial sums across the 4 fi-phases (lane bits 4,5)
#pragma unroll
        for (int n = 0; n < 8; ++n) {
            acc[n].x += __shfl_xor(acc[n].x, 16, 64);
            acc[n].y += __shfl_xor(acc[n].y, 16, 64);
            acc[n].z += __shfl_xor(acc[n].z, 16, 64);
            acc[n].w += __shfl_xor(acc[n].w, 16, 64);
            acc[n].x += __shfl_xor(acc[n].x, 32, 64);
            acc[n].y += __shfl_xor(acc[n].y, 32, 64);
            acc[n].z += __shfl_xor(acc[n].z, 32, 64);
            acc[n].w += __shfl_xor(acc[n].w, 32, 64);
        }

        const float4 as4 = *(const float4*)(a_src + hh * FOUT + 4 * og);
        const float4 ad4 = *(const float4*)(a_dst + hh * FOUT + 4 * og);
#pragma unroll
        for (int n = 0; n < 8; ++n) {
            // store: fi-group (n>>1) writes node n (static acc index, masked)
            if ((n >> 1) == fi)
                *(float4*)(h_prime + ((size_t)hh * NN + n0 + n) * FOUT + 4 * og) = acc[n];
            float ps = acc[n].x * as4.x + acc[n].y * as4.y +
                       acc[n].z * as4.z + acc[n].w * as4.w;
            float pd = acc[n].x * ad4.x + acc[n].y * ad4.y +
                       acc[n].z * ad4.z + acc[n].w * ad4.w;
#pragma unroll
            for (int off = 1; off <= 8; off <<= 1) {
                ps += __shfl_xor(ps, off, 64);     // reduce over og (bits 0-3)
                pd += __shfl_xor(pd, off, 64);
            }
            if (lane == 0) {
                src[hh * NN + n0 + n] = ps;
                dst[hh * NN + n0 + n] = pd;
            }
        }
    }
}

// ---------------------------------------------------------------------------
// K2: attn from bitmask. Block = row i. Wave 0 decodes the 512B mask into an
// LDS edge list (popc prefix + ffs extraction), then scores / per-head
// softmax (wave = head) / 8-deep batched gather, as in r8.
// ---------------------------------------------------------------------------
__global__ __launch_bounds__(256) void gat_attn(
    const unsigned long long* __restrict__ bits,
    const float* __restrict__ h_prime, const float* __restrict__ src,
    const float* __restrict__ dst, const float* __restrict__ bias,
    float* __restrict__ out)
{
    const int i = blockIdx.x, t = threadIdx.x, wv = t >> 6, lane = t & 63;

    __shared__ int   idx_l[CAP];
    __shared__ float sc[NH][CAP];
    __shared__ int   cnt;
    __shared__ float inv_sum[NH];

    if (wv == 0) {
        unsigned long long m = bits[(size_t)i * 64 + lane];
        const int c = __popcll(m);
        int pre = c;
#pragma unroll
        for (int off = 1; off < 64; off <<= 1) {
            const int nb = __shfl_up(pre, off, 64);
            if (lane >= off) pre += nb;
        }
        int p = pre - c;
        const int cb = (lane >> 2) * 256 + (lane & 3);
        while (m) {
            const int bpos = __ffsll((unsigned long long)m) - 1;
            if (p < CAP) idx_l[p] = cb + 4 * bpos;
            ++p;
            m &= m - 1;
        }
        if (lane == 63) cnt = pre;
    }
    __syncthreads();

    const int count = min(cnt, CAP);
    const int cpad  = (count + 7) & ~7;

    // scores (t -> edge t) + zero-padding to cpad
    if (t < count) {
        const int j = idx_l[t];
#pragma unroll
        for (int hh = 0; hh < NH; ++hh) {
            const float v = src[hh * NN + i] + dst[hh * NN + j];
            sc[hh][t] = (v >= 0.f) ? v : 0.2f * v;   // leaky_relu(0.2)
        }
    } else if (t < cpad) {
        idx_l[t] = 0;
#pragma unroll
        for (int hh = 0; hh < NH; ++hh) sc[hh][t] = 0.f;
    }
    __syncthreads();

    // per-head softmax (wave = head)
    {
        float m = -3.4e38f;
        for (int p = lane; p < count; p += 64) m = fmaxf(m, sc[wv][p]);
#pragma unroll
        for (int off = 32; off >= 1; off >>= 1) m = fmaxf(m, __shfl_xor(m, off, 64));
        float e = 0.f;
        for (int p = lane; p < count; p += 64) {
            const float v = __expf(sc[wv][p] - m);
            sc[wv][p] = v;
            e += v;
        }
#pragma unroll
        for (int off = 32; off >= 1; off >>= 1) e += __shfl_xor(e, off, 64);
        if (lane == 0) inv_sum[wv] = 1.f / e;
    }
    __syncthreads();

    // gather, 8 independent loads in flight per batch
    float accv = 0.f;
    const float* hp = h_prime + (size_t)(wv * NN) * FOUT + lane;
    for (int p0 = 0; p0 < cpad; p0 += 8) {
        int jj[8]; float vv[8]; float ww[8];
#pragma unroll
        for (int k = 0; k < 8; ++k) jj[k] = idx_l[p0 + k];
#pragma unroll
        for (int k = 0; k < 8; ++k) vv[k] = hp[(size_t)jj[k] * FOUT];
#pragma unroll
        for (int k = 0; k < 8; ++k) ww[k] = sc[wv][p0 + k];
#pragma unroll
        for (int k = 0; k < 8; ++k) accv = fmaf(ww[k], vv[k], accv);
    }
    out[(size_t)i * (NH * FOUT) + wv * FOUT + lane] = accv * inv_sum[wv] + bias[lane];
}

extern "C" void kernel_launch(void* const* d_in, const int* in_sizes, int n_in,
                              void* d_out, int out_size, void* d_ws, size_t ws_size,
                              hipStream_t stream) {
    const float* h     = (const float*)d_in[0];
    const int*   adj   = (const int*)d_in[1];
    const float* w     = (const float*)d_in[2];
    const float* a_src = (const float*)d_in[3];
    const float* a_dst = (const float*)d_in[4];
    const float* bias  = (const float*)d_in[5];
    float* out = (float*)d_out;

    float* wsf     = (float*)d_ws;
    float* h_prime = wsf;                        // NH*NN*FOUT floats = 4 MB
    float* src     = h_prime + NH * NN * FOUT;   // NH*NN floats
    float* dst     = src + NH * NN;              // NH*NN floats
    unsigned long long* bits = (unsigned long long*)(dst + NH * NN);  // 2 MB

    gat_prep<<<CPB + HPBK, 256, 0, stream>>>(h, adj, w, a_src, a_dst,
                                             h_prime, src, dst, bits);
    gat_attn<<<NN, 256, 0, stream>>>(bits, h_prime, src, dst, bias, out);
}